// Round 4
// baseline (1644.195 us; speedup 1.0000x reference)
//
#include <hip/hip_runtime.h>
#include <hip/hip_bf16.h>
#include <stdint.h>

// Model: B=4 S=4096 D=768 H=12 DH=64 BS=64 NB=64 NSEL=8 L=2 FF=3072 M=16384
// Round 9: 256x256 GEMM (gemm256) for QKV/FF1/FF2:
//  - 512 thr / 8 waves (2M x 4N), wave tile 128x64, acc[8][4], BK=64
//  - 2 LDS buffers (128 KB), stage-all-8 at iter top, counted vmcnt(8)
//  - 4 MFMA-quadrant phases per iter, s_barrier between, setprio(1) around MFMA
//  - chunk-XOR LDS swizzle (row&7) -> conflict-free ds_read_b128 at 128B row stride
//  AO keeps the 128-tile ABLK kernel.

using bf16 = __hip_bfloat16;
typedef __bf16 bf16x8 __attribute__((ext_vector_type(8)));
typedef __bf16 bf16x4 __attribute__((ext_vector_type(4)));
typedef float f32x4 __attribute__((ext_vector_type(4)));

__device__ __forceinline__ float b2f(bf16 x) { return __bfloat162float(x); }
__device__ __forceinline__ bf16 f2b(float x) { return __float2bfloat16(x); }
__device__ __forceinline__ __bf16 f2br(float x) {
  bf16 h = __float2bfloat16(x);
  return *reinterpret_cast<__bf16*>(&h);
}
__device__ __forceinline__ float br2f(__bf16 x) {
  bf16 t; *reinterpret_cast<__bf16*>(&t) = x; return __bfloat162float(t);
}
// flag=1: raw input buffers hold bf16; flag=0: f32.
__device__ __forceinline__ float ldf(const void* p, size_t i, int flag) {
  return flag ? __bfloat162float(((const bf16*)p)[i]) : ((const float*)p)[i];
}

__device__ __forceinline__ void gld_lds16(const bf16* g, bf16* l) {
  __builtin_amdgcn_global_load_lds((__attribute__((address_space(1))) void*)g,
                                   (__attribute__((address_space(3))) void*)l, 16, 0, 0);
}

__device__ __forceinline__ f32x4 mfma16(bf16x8 a, bf16x8 b, f32x4 c) {
  return __builtin_amdgcn_mfma_f32_16x16x32_bf16(a, b, c, 0, 0, 0);
}

// gelu(tanh approx) == x * sigmoid(2*0.79788456*(x + 0.044715 x^3))
__device__ __forceinline__ float gelu_f(float x) {
  const float z = 1.5957691216057308f * (x + 0.044715f * x * x * x);
  return x / (1.0f + __expf(-z));
}

// ---------------- dtype probe: ln_emb_g is all ones ----------------
__global__ void probe_kernel(const uint32_t* __restrict__ g, int* __restrict__ flag) {
  if (threadIdx.x == 0) flag[0] = (g[0] == 0x3F803F80u) ? 1 : 0;
}

// ---------------- weight transpose+convert ----------------
__global__ __launch_bounds__(256) void transpose_k(const void* __restrict__ in, size_t in_off,
                                                   bf16* __restrict__ out, int K, int N,
                                                   const int* __restrict__ dflag) {
  __shared__ float tile[32][33];
  const int flag = dflag[0];
  const int bx = blockIdx.x * 32;  // n
  const int by = blockIdx.y * 32;  // k
  const int tx = threadIdx.x & 31, ty = threadIdx.x >> 5;  // 32x8
#pragma unroll
  for (int i = 0; i < 32; i += 8)
    tile[ty + i][tx] = ldf(in, in_off + (size_t)(by + ty + i) * N + bx + tx, flag);
  __syncthreads();
#pragma unroll
  for (int i = 0; i < 32; i += 8)
    out[(size_t)(bx + ty + i) * K + by + tx] = f2b(tile[tx][ty + i]);
}

// ---------------- embedding + LN ----------------
__global__ __launch_bounds__(256) void embed_ln_kernel(
    const int* __restrict__ ids, const void* __restrict__ emb, const void* __restrict__ pos,
    const void* __restrict__ g, const void* __restrict__ bb, bf16* __restrict__ h,
    const int* __restrict__ dflag) {
  __shared__ float red[8];
  const int flag = dflag[0];
  const int tok = blockIdx.x;
  const int tid = threadIdx.x;
  const int s = tok & 4095;
  const size_t id = (size_t)ids[tok];
  float v[3]; float sum = 0.f, sq = 0.f;
#pragma unroll
  for (int i = 0; i < 3; i++) {
    const int d = tid + i * 256;
    v[i] = ldf(emb, id * 768 + d, flag) + ldf(pos, (size_t)s * 768 + d, flag);
    sum += v[i]; sq += v[i] * v[i];
  }
#pragma unroll
  for (int off = 32; off >= 1; off >>= 1) { sum += __shfl_down(sum, off); sq += __shfl_down(sq, off); }
  if ((tid & 63) == 0) { red[(tid >> 6) * 2] = sum; red[(tid >> 6) * 2 + 1] = sq; }
  __syncthreads();
  sum = red[0] + red[2] + red[4] + red[6];
  sq  = red[1] + red[3] + red[5] + red[7];
  const float mean = sum * (1.0f / 768.0f);
  const float var = sq * (1.0f / 768.0f) - mean * mean;
  const float rs = rsqrtf(var + 1e-12f);
  bf16* hr = h + (size_t)tok * 768;
#pragma unroll
  for (int i = 0; i < 3; i++) {
    const int d = tid + i * 256;
    hr[d] = f2b((v[i] - mean) * rs * ldf(g, d, flag) + ldf(bb, d, flag));
  }
}

// ---------------- residual add + LN (in-place on h), 1 wave per token ----------------
__global__ __launch_bounds__(256) void add_ln_kernel(
    bf16* __restrict__ h, const bf16* __restrict__ x,
    const void* __restrict__ g, const void* __restrict__ bb, size_t goff,
    const int* __restrict__ dflag) {
  const int flag = dflag[0];
  const int tid = threadIdx.x;
  const int wv = tid >> 6, lane = tid & 63;
  const int tok = blockIdx.x * 4 + wv;
  const size_t base = (size_t)tok * 768;

  float v[16];
  float sum = 0.f, sq = 0.f;
  const bf16x8 h0 = *(const bf16x8*)(h + base + lane * 8);
  const bf16x8 x0 = *(const bf16x8*)(x + base + lane * 8);
#pragma unroll
  for (int j = 0; j < 8; j++) {
    const float t = br2f(h0[j]) + br2f(x0[j]);
    v[j] = t; sum += t; sq += t * t;
  }
  if (lane < 32) {
    const bf16x8 h1 = *(const bf16x8*)(h + base + 512 + lane * 8);
    const bf16x8 x1 = *(const bf16x8*)(x + base + 512 + lane * 8);
#pragma unroll
    for (int j = 0; j < 8; j++) {
      const float t = br2f(h1[j]) + br2f(x1[j]);
      v[8 + j] = t; sum += t; sq += t * t;
    }
  }
#pragma unroll
  for (int off = 32; off >= 1; off >>= 1) { sum += __shfl_xor(sum, off); sq += __shfl_xor(sq, off); }
  const float mean = sum * (1.0f / 768.0f);
  const float var = sq * (1.0f / 768.0f) - mean * mean;
  const float rs = rsqrtf(var + 1e-12f);

  bf16x8 o0;
#pragma unroll
  for (int j = 0; j < 8; j++) {
    const int d = lane * 8 + j;
    o0[j] = f2br((v[j] - mean) * rs * ldf(g, goff + d, flag) + ldf(bb, goff + d, flag));
  }
  *(bf16x8*)(h + base + lane * 8) = o0;
  if (lane < 32) {
    bf16x8 o1;
#pragma unroll
    for (int j = 0; j < 8; j++) {
      const int d = 512 + lane * 8 + j;
      o1[j] = f2br((v[8 + j] - mean) * rs * ldf(g, goff + d, flag) + ldf(bb, goff + d, flag));
    }
    *(bf16x8*)(h + base + 512 + lane * 8) = o1;
  }
}

// ---------------- 256x256 GEMM: C[M,N] = A @ Bt^T + bias ----------------
// EPI 0: plain store. EPI 1: gelu. EPI 2: scatter into blocked q/k/vT.
// A row-major [M][K], Bt row-major [N][K]. 512 threads, 8 waves (2M x 4N),
// wave tile 128x64, BK=64. 2 LDS buffers (A 32KB + B 32KB each).
// LDS rows are 64 elems (128B); 16B chunk c of row r stored at slot c^(r&7)
// (inverse-swizzled global source, linear gld_lds dest; reads apply same XOR).
template <int EPI>
__global__ __launch_bounds__(512) void gemm256(
    const bf16* __restrict__ A, const bf16* __restrict__ Bt,
    const void* __restrict__ bias, size_t bias_off, bf16* __restrict__ C,
    int N, int K,
    bf16* __restrict__ qout, bf16* __restrict__ kout, bf16* __restrict__ vout,
    const int* __restrict__ dflag) {
  __shared__ __align__(16) bf16 smem[65536];   // 2 x (A 16384 + B 16384)
  const int m0 = blockIdx.x * 256;
  const int n0 = blockIdx.y * 256;
  const int tid = threadIdx.x;
  const int lane = tid & 63;
  const int wv = tid >> 6;
  const int wm = wv >> 2, wn = wv & 3;         // 2 x 4 wave grid
  const int col = lane & 15, quad = lane >> 4;

  f32x4 acc[8][4] = {};

  // Staging geometry: per gld instr, thread t -> row t>>3 (of 64), slot t&7.
  // Global source chunk = slot ^ (row&7)  (row&7 invariant under +64 rows).
  const int rS = tid >> 3, slS = tid & 7;
  const int swz = (slS ^ (rS & 7)) << 3;       // element offset of source chunk
  const bf16* gA = A + (size_t)(m0 + rS) * K + swz;
  const bf16* gB = Bt + (size_t)(n0 + rS) * K + swz;
  const size_t rowstep = (size_t)64 * K;

  auto stage = [&](int buf, int kt) {
    bf16* dA = smem + buf * 32768;
    bf16* dB = dA + 16384;
    const int kk = kt * 64;
#pragma unroll
    for (int i = 0; i < 4; i++)
      gld_lds16(gA + (size_t)i * rowstep + kk, dA + i * 4096 + tid * 8);
#pragma unroll
    for (int i = 0; i < 4; i++)
      gld_lds16(gB + (size_t)i * rowstep + kk, dB + i * 4096 + tid * 8);
  };

  const int nkt = K >> 6;
  stage(0, 0);

  // Fragment read bases: row = base + {m,n}*16 + col; slot = (kh*4+quad)^(col&7)
  const int arow = wm * 128 + col;
  const int brow = wn * 64 + col;
  const int s7 = col & 7;

  for (int it = 0; it < nkt; ++it) {
    const int cur = it & 1;
    if (it + 1 < nkt) {
      stage(cur ^ 1, it + 1);
      asm volatile("s_waitcnt vmcnt(8)" ::: "memory");  // tile 'it' landed; next 8 in flight
    } else {
      asm volatile("s_waitcnt vmcnt(0)" ::: "memory");
    }
    __builtin_amdgcn_s_barrier();
    asm volatile("" ::: "memory");

    const bf16* cA = smem + cur * 32768;
    const bf16* cB = cA + 16384;
#pragma unroll
    for (int kh = 0; kh < 2; kh++) {
      const int ksl = ((kh * 4 + quad) ^ s7) << 3;
      bf16x8 bv[4];
#pragma unroll
      for (int n = 0; n < 4; n++)
        bv[n] = *(const bf16x8*)(cB + (brow + n * 16) * 64 + ksl);
#pragma unroll
      for (int mh = 0; mh < 2; mh++) {
        bf16x8 av[4];
#pragma unroll
        for (int m = 0; m < 4; m++)
          av[m] = *(const bf16x8*)(cA + (arow + (mh * 4 + m) * 16) * 64 + ksl);
        __builtin_amdgcn_s_setprio(1);
#pragma unroll
        for (int m = 0; m < 4; m++)
#pragma unroll
          for (int n = 0; n < 4; n++)
            acc[mh * 4 + m][n] = mfma16(av[m], bv[n], acc[mh * 4 + m][n]);
        __builtin_amdgcn_s_setprio(0);
        asm volatile("" ::: "memory");
        __builtin_amdgcn_s_barrier();    // phase lockstep; last one = iter-end barrier
      }
    }
  }

  const int flag = dflag[0];
  float bsv[4];
#pragma unroll
  for (int nt = 0; nt < 4; nt++)
    bsv[nt] = ldf(bias, bias_off + n0 + wn * 64 + nt * 16 + col, flag);

  if constexpr (EPI != 2) {
    // 4 passes of 64 rows, LDS pitch 264 elems, then vectorized copy-out.
    for (int P = 0; P < 4; P++) {
      __syncthreads();
      if (wm == (P >> 1)) {
        const int mh = P & 1;
#pragma unroll
        for (int nt = 0; nt < 4; nt++)
#pragma unroll
          for (int m = 0; m < 4; m++)
#pragma unroll
            for (int r = 0; r < 4; r++) {
              float val = acc[mh * 4 + m][nt][r] + bsv[nt];
              if constexpr (EPI == 1) val = gelu_f(val);
              smem[(m * 16 + quad * 4 + r) * 264 + wn * 64 + nt * 16 + col] = f2b(val);
            }
      }
      __syncthreads();
#pragma unroll
      for (int j = 0; j < 4; j++) {
        const int c2 = j * 512 + tid;          // 2048 chunks of 8
        const int row = c2 >> 5, cc = c2 & 31;
        const bf16x8 vv = *(const bf16x8*)(smem + row * 264 + cc * 8);
        *(bf16x8*)(C + (size_t)(m0 + P * 64 + row) * N + n0 + cc * 8) = vv;
      }
    }
  } else {
    // QKV scatter: tile = 4 nb-blocks x 4 heads of one part (no straddle:
    // N=2304=3*768, 768%256==0; tokens 256 | 4096 per batch).
    const int part = n0 / 768;
    const int w0 = n0 - part * 768;
    const int h0 = w0 >> 6;
    const int bb = m0 >> 12;
    const int nb0 = (m0 >> 6) & 63;
    for (int P = 0; P < 4; P++) {
      __syncthreads();
      if (wm == (P >> 1)) {
        const int mh = P & 1;
        if (part < 2) {
#pragma unroll
          for (int nt = 0; nt < 4; nt++)
#pragma unroll
            for (int m = 0; m < 4; m++)
#pragma unroll
              for (int r = 0; r < 4; r++)
                smem[(m * 16 + quad * 4 + r) * 264 + wn * 64 + nt * 16 + col] =
                    f2b(acc[mh * 4 + m][nt][r] + bsv[nt]);
        } else {
          // V: stage transposed [ncol][pos], pitch 72
#pragma unroll
          for (int nt = 0; nt < 4; nt++) {
            const int ncol = wn * 64 + nt * 16 + col;
#pragma unroll
            for (int m = 0; m < 4; m++) {
              bf16x4 pk;
#pragma unroll
              for (int r = 0; r < 4; r++) pk[r] = f2br(acc[mh * 4 + m][nt][r] + bsv[nt]);
              *(bf16x4*)(smem + ncol * 72 + m * 16 + quad * 4) = pk;
            }
          }
        }
      }
      __syncthreads();
      const size_t nbase = (size_t)((bb * 12 + h0) * 64 + nb0 + P) * 4096;
      if (part < 2) {
        bf16* dst = (part == 0) ? qout : kout;
        const int pos = tid >> 3, pc = tid & 7;
#pragma unroll
        for (int j = 0; j < 4; j++) {
          const bf16x8 vv = *(const bf16x8*)(smem + pos * 264 + j * 64 + pc * 8);
          *(bf16x8*)(dst + nbase + (size_t)j * 262144 + pos * 64 + pc * 8) = vv;
        }
      } else {
        const int dh = tid >> 3, pc = tid & 7;
#pragma unroll
        for (int j = 0; j < 4; j++) {
          const bf16x8 vv = *(const bf16x8*)(smem + (j * 64 + dh) * 72 + pc * 8);
          *(bf16x8*)(vout + nbase + (size_t)j * 262144 + dh * 64 + pc * 8) = vv;
        }
      }
    }
  }
}

// ---------------- 128-tile GEMM (kept for AO): C[M,N] = A @ Bt^T + bias ----------------
// ABLK: A is blocked [bb][hh][nb][pos][dh]. Depth-2 pipeline, 3 buffers.
template <int EPI, bool ABLK>
__global__ __launch_bounds__(256) void gemm_bt(
    const bf16* __restrict__ A, const bf16* __restrict__ Bt,
    const void* __restrict__ bias, size_t bias_off, bf16* __restrict__ C,
    int N, int K,
    bf16* __restrict__ qout, bf16* __restrict__ kout, bf16* __restrict__ vout,
    const int* __restrict__ dflag) {
  __shared__ __align__(16) bf16 smem[24576];
  const int m0 = blockIdx.x * 128;
  const int n0 = blockIdx.y * 128;
  const int tid = threadIdx.x;
  const int lane = tid & 63;
  const int wv = tid >> 6;
  const int wm = wv >> 1, wn = wv & 1;
  const int col = lane & 15, quad = lane >> 4;

  f32x4 acc[4][4] = {};

  const int sr = tid >> 2;
  const int kc = ((tid & 3) - ((tid >> 4) & 3)) & 3;
  const int sc = kc * 8;
  const bf16* gA = A + (size_t)(m0 + sr) * K + sc;
  const bf16* gB = Bt + (size_t)(n0 + sr) * K + sc;
  const size_t rstep = (size_t)64 * K;

  size_t cb0 = 0, cb1 = 0;
  if constexpr (ABLK) {
    const int t0 = m0 + sr, t1 = t0 + 64;
    cb0 = (size_t)(t0 >> 12) * 3145728 + ((t0 >> 6) & 63) * 4096 + (t0 & 63) * 64;
    cb1 = (size_t)(t1 >> 12) * 3145728 + ((t1 >> 6) & 63) * 4096 + (t1 & 63) * 64;
  }

  const int sl = (quad + (col >> 2)) & 3;

  auto stage = [&](int buf, int kk) {
    bf16* dA = smem + buf * 8192;
    bf16* dB = dA + 4096;
    const bf16 *pA0, *pA1;
    if constexpr (ABLK) {
      const int c = kk + sc;
      const int hh = c >> 6, dh = c & 63;
      pA0 = A + cb0 + hh * 262144 + dh;
      pA1 = A + cb1 + hh * 262144 + dh;
    } else {
      pA0 = gA + kk; pA1 = gA + rstep + kk;
    }
    gld_lds16(pA0, dA + tid * 8);
    gld_lds16(pA1, dA + 2048 + tid * 8);
    gld_lds16(gB + kk, dB + tid * 8);
    gld_lds16(gB + rstep + kk, dB + 2048 + tid * 8);
  };

  const int nIter = K >> 5;
  stage(0, 0);
  stage(1, 32);

  int cur = 0, pf = 2;
  for (int it = 0; it < nIter; ++it) {
    if (it + 2 < nIter) {
      stage(pf, (it + 2) * 32);
      pf = (pf == 2) ? 0 : pf + 1;
      asm volatile("s_waitcnt vmcnt(8)" ::: "memory");
    } else if (it + 1 < nIter) {
      asm volatile("s_waitcnt vmcnt(4)" ::: "memory");
    } else {
      asm volatile("s_waitcnt vmcnt(0)" ::: "memory");
    }
    __builtin_amdgcn_s_barrier();
    asm volatile("" ::: "memory");

    const bf16* cA = smem + cur * 8192;
    const bf16* cB = cA + 4096;
    bf16x8 av[4], bv[4];
#pragma unroll
    for (int t = 0; t < 4; t++)
      av[t] = *(const bf16x8*)(cA + (wm * 64 + t * 16 + col) * 32 + sl * 8);
#pragma unroll
    for (int t = 0; t < 4; t++)
      bv[t] = *(const bf16x8*)(cB + (wn * 64 + t * 16 + col) * 32 + sl * 8);
#pragma unroll
    for (int mt = 0; mt < 4; mt++)
#pragma unroll
      for (int nt = 0; nt < 4; nt++)
        acc[mt][nt] = mfma16(av[mt], bv[nt], acc[mt][nt]);

    asm volatile("" ::: "memory");
    __builtin_amdgcn_s_barrier();
    cur = (cur == 2) ? 0 : cur + 1;
  }

  const int flag = dflag[0];
  float bsv[4];
#pragma unroll
  for (int nt = 0; nt < 4; nt++)
    bsv[nt] = ldf(bias, bias_off + n0 + wn * 64 + nt * 16 + col, flag);

  // Single-pass LDS-staged coalesced store (EPI 0/1 only used for AO here).
#pragma unroll
  for (int nt = 0; nt < 4; nt++)
#pragma unroll
    for (int mt = 0; mt < 4; mt++)
#pragma unroll
      for (int r = 0; r < 4; r++) {
        float val = acc[mt][nt][r] + bsv[nt];
        if constexpr (EPI == 1) val = gelu_f(val);
        smem[(wm * 64 + mt * 16 + quad * 4 + r) * 136 + wn * 64 + nt * 16 + col] = f2b(val);
      }
  __syncthreads();
#pragma unroll
  for (int rr = 0; rr < 8; rr++) {
    const int row = rr * 16 + (tid >> 4);
    const int ch = tid & 15;
    const bf16x8 vv = *(const bf16x8*)(smem + row * 136 + ch * 8);
    *(bf16x8*)(C + (size_t)(m0 + row) * N + n0 + ch * 8) = vv;
  }
  (void)qout; (void)kout; (void)vout;
}

// ---------------- block-sparse flash attention, full batch ----------------
__global__ __launch_bounds__(256, 4) void attn_kernel(
    const bf16* q, const bf16* __restrict__ kmat, const bf16* __restrict__ vT,
    const int* __restrict__ amask, const int* __restrict__ rand_idx, bf16* o) {
  __shared__ __align__(16) bf16 sK[2][4096];
  __shared__ __align__(16) bf16 sV[2][4096];
  const int idx = blockIdx.x;
  const int nb = idx & 63;
  const int bh = idx >> 6;
  const int bb = bh / 12;
  const int tid = threadIdx.x;
  const int wv = tid >> 6, lane = tid & 63;
  const int col = lane & 15, quad = lane >> 4;

  int sel[8];
  sel[0] = 0; sel[1] = (nb + 63) & 63; sel[2] = nb; sel[3] = (nb + 1) & 63;
  sel[4] = 63;
  sel[5] = rand_idx[nb * 3 + 0];
  sel[6] = rand_idx[nb * 3 + 1];
  sel[7] = rand_idx[nb * 3 + 2];

  const size_t bhbase = (size_t)bh * 64;

  const bf16* qb = q + (bhbase + nb) * 4096;
  const int qrow = wv * 16 + col;
  const bf16x8 bq0 = *(const bf16x8*)(qb + qrow * 64 + quad * 8);
  const bf16x8 bq1 = *(const bf16x8*)(qb + qrow * 64 + 32 + quad * 8);

  unsigned long long bal[8];
#pragma unroll
  for (int sb = 0; sb < 8; sb++)
    bal[sb] = __ballot(amask[bb * 4096 + sel[sb] * 64 + lane] > 0);

  const int srow = tid >> 3, sslot = tid & 7;
  const int sw0 = ((sslot ^ (srow & 7)) << 3);

  auto stage = [&](int buf, int blk) {
    const bf16* gk = kmat + (bhbase + blk) * 4096;
    const bf16* gv = vT + (bhbase + blk) * 4096;
    bf16* dk = sK[buf];
    bf16* dv = sV[buf];
    gld_lds16(gk + srow * 64 + sw0, dk + tid * 8);
    gld_lds16(gk + (srow + 32) * 64 + sw0, dk + 2048 + tid * 8);
    gld_lds16(gv + srow * 64 + sw0, dv + tid * 8);
    gld_lds16(gv + (srow + 32) * 64 + sw0, dv + 2048 + tid * 8);
  };

  f32x4 oacc[4] = {};
  float mrun = -1e30f, lrun = 0.0f;

  stage(0, sel[0]);

#pragma unroll
  for (int sb = 0; sb < 8; sb++) {
    const int cur = sb & 1;
    if (sb < 7) {
      stage(cur ^ 1, sel[sb + 1]);
      asm volatile("s_waitcnt vmcnt(4)" ::: "memory");
    } else {
      asm volatile("s_waitcnt vmcnt(0)" ::: "memory");
    }
    __builtin_amdgcn_s_barrier();
    asm volatile("" ::: "memory");

    const bf16* kb = sK[cur];
    f32x4 t[4];
#pragma unroll
    for (int c = 0; c < 4; c++) {
      const int r = c * 16 + col;
      const bf16x8 ak0 = *(const bf16x8*)(kb + r * 64 + ((quad ^ (r & 7)) << 3));
      const bf16x8 ak1 = *(const bf16x8*)(kb + r * 64 + (((4 + quad) ^ (r & 7)) << 3));
      f32x4 s4 = {};
      s4 = mfma16(ak0, bq0, s4);
      s4 = mfma16(ak1, bq1, s4);
      t[c] = s4;
    }
#pragma unroll
    for (int c = 0; c < 4; c++)
#pragma unroll
      for (int r = 0; r < 4; r++) t[c][r] *= 0.125f;
    if (bal[sb] != ~0ull) {
#pragma unroll
      for (int c = 0; c < 4; c++)
#pragma unroll
        for (int r = 0; r < 4; r++)
          if (!((bal[sb] >> (c * 16 + quad * 4 + r)) & 1)) t[c][r] -= 1e9f;
    }

    float pm = t[0][0];
#pragma unroll
    for (int c = 0; c < 4; c++)
#pragma unroll
      for (int r = 0; r < 4; r++) pm = fmaxf(pm, t[c][r]);
    pm = fmaxf(pm, __shfl_xor(pm, 16));
    pm = fmaxf(pm, __shfl_xor(pm, 32));

    const float mnew = fmaxf(mrun, pm);
    const float scale = __expf(mrun - mnew);
    float ps = 0.0f;
    bf16x8 pa8[2];
#pragma unroll
    for (int c = 0; c < 4; c++)
#pragma unroll
      for (int r = 0; r < 4; r++) {
        const float p = __expf(t[c][r] - mnew);
        ps += p;
        pa8[c >> 1][(c & 1) * 4 + r] = f2br(p);
      }
    ps += __shfl_xor(ps, 16);
    ps += __shfl_xor(ps, 32);
    lrun = lrun * scale + ps;
    mrun = mnew;

    float sc[4];
#pragma unroll
    for (int r = 0; r < 4; r++) sc[r] = __shfl(scale, quad * 4 + r);
#pragma unroll
    for (int nt = 0; nt < 4; nt++)
#pragma unroll
      for (int r = 0; r < 4; r++) oacc[nt][r] *= sc[r];

    const bf16* vb = sV[cur];
#pragma unroll
    for (int pr = 0; pr < 2; pr++) {
      const int g0 = 4 * pr + (quad >> 1);
      const int g1 = g0 + 2;
      const int so = (quad & 1) * 4;
#pragma unroll
      for (int nt = 0; nt < 4; nt++) {
        const int dh = nt * 16 + col;
        const bf16x4 bv0 = *(const bf16x4*)(vb + dh * 64 + ((g0 ^ (col & 7)) << 3) + so);
        const bf16x4 bv1 = *(const bf16x4*)(vb + dh * 64 + ((g1 ^ (col & 7)) << 3) + so);
        const bf16x8 bv8 = __builtin_shufflevector(bv0, bv1, 0, 1, 2, 3, 4, 5, 6, 7);
        oacc[nt] = mfma16(pa8[pr], bv8, oacc[nt]);
      }
    }
    asm volatile("" ::: "memory");
    __builtin_amdgcn_s_barrier();
  }

  const float invl = 1.0f / lrun;
  float iv[4];
#pragma unroll
  for (int r = 0; r < 4; r++) iv[r] = __shfl(invl, quad * 4 + r);
  bf16* ob = o + (bhbase + nb) * 4096;
#pragma unroll
  for (int nt = 0; nt < 4; nt++)
#pragma unroll
    for (int r = 0; r < 4; r++)
      ob[(wv * 16 + quad * 4 + r) * 64 + nt * 16 + col] = f2b(oacc[nt][r] * iv[r]);
}

// ---------------- pooler ----------------
__global__ __launch_bounds__(768) void pooler_kernel(
    const bf16* __restrict__ h, const void* __restrict__ Wp,
    const void* __restrict__ bp, float* __restrict__ pooled,
    const int* __restrict__ dflag) {
  __shared__ float hrow[768];
  const int flag = dflag[0];
  const int bb = blockIdx.x;
  const int j = threadIdx.x;
  hrow[j] = b2f(h[(size_t)bb * 4096 * 768 + j]);
  __syncthreads();
  float acc = 0.0f;
#pragma unroll 8
  for (int d = 0; d < 768; d++) acc += hrow[d] * ldf(Wp, (size_t)d * 768 + j, flag);
  pooled[bb * 768 + j] = tanhf(acc + ldf(bp, j, flag));
}

// ---------------- classifier + double-softmax loss ----------------
__global__ __launch_bounds__(256) void cls_kernel(
    const float* __restrict__ pooled, const void* __restrict__ Wc, const void* __restrict__ bc,
    const int* __restrict__ label, void* __restrict__ out, const int* __restrict__ dflag) {
  __shared__ float lsum[8];
  const int flag = dflag[0];
  const int tid = threadIdx.x;
  const int p = tid >> 5, i = tid & 31;
  const int bb = p >> 1, c = p & 1;
  float acc = 0.0f;
  for (int d = i; d < 768; d += 32) acc += pooled[bb * 768 + d] * ldf(Wc, (size_t)d * 2 + c, flag);
#pragma unroll
  for (int off = 16; off >= 1; off >>= 1) acc += __shfl_xor(acc, off);
  if (i == 0) lsum[p] = acc;
  __syncthreads();
  if (tid == 0) {
    float res[9];
    float loss = 0.0f;
    for (int b = 0; b < 4; b++) {
      const float l0 = lsum[b * 2 + 0] + ldf(bc, 0, flag);
      const float l1 = lsum[b * 2 + 1] + ldf(bc, 1, flag);
      const float m = fmaxf(l0, l1);
      const float e0 = expf(l0 - m), e1 = expf(l1 - m);
      const float s = e0 + e1;
      const float p0 = e0 / s, p1 = e1 / s;
      res[b * 2] = p0; res[b * 2 + 1] = p1;
      const float mm = fmaxf(p0, p1);
      const float lse = mm + logf(expf(p0 - mm) + expf(p1 - mm));
      const float chosen = (label[b] == 0) ? p0 : p1;
      loss -= (chosen - lse);
    }
    res[8] = loss * 0.25f;
    if (flag) { bf16* o = (bf16*)out; for (int j = 0; j < 9; j++) o[j] = f2b(res[j]); }
    else      { float* o = (float*)out; for (int j = 0; j < 9; j++) o[j] = res[j]; }
  }
}

extern "C" void kernel_launch(void* const* d_in, const int* in_sizes, int n_in,
                              void* d_out, int out_size, void* d_ws, size_t ws_size,
                              hipStream_t stream) {
  const int* input_ids      = (const int*)d_in[0];
  const int* attention_mask = (const int*)d_in[1];
  const int* label          = (const int*)d_in[2];
  const int* rand_idx       = (const int*)d_in[3];
  const void* emb      = d_in[4];
  const void* pos_emb  = d_in[5];
  const void* ln_emb_g = d_in[6];
  const void* ln_emb_b = d_in[7];
  const void* Wqkv = d_in[8];
  const void* bqkv = d_in[9];
  const void* Wo   = d_in[10];
  const void* bo   = d_in[11];
  const void* ln1_g = d_in[12];
  const void* ln1_b = d_in[13];
  const void* Wff1 = d_in[14];
  const void* bff1 = d_in[15];
  const void* Wff2 = d_in[16];
  const void* bff2 = d_in[17];
  const void* ln2_g = d_in[18];
  const void* ln2_b = d_in[19];
  const void* Wp = d_in[20];
  const void* bp = d_in[21];
  const void* Wc = d_in[22];
  const void* bc = d_in[23];

  bf16* ws = (bf16*)d_ws;
  size_t off = 0;
  int* dflag = (int*)(ws + off); off += 8;
  bf16* WqkvT = ws + off; off += (size_t)2 * 2304 * 768;
  bf16* WoT   = ws + off; off += (size_t)2 * 768 * 768;
  bf16* Wff1T = ws + off; off += (size_t)2 * 3072 * 768;
  bf16* Wff2T = ws + off; off += (size_t)2 * 768 * 3072;
  bf16* hbuf  = ws + off; off += (size_t)16384 * 768;
  bf16* qo    = ws + off; off += (size_t)16384 * 768;   // Q then O (blocked)
  bf16* kbf   = ws + off; off += (size_t)16384 * 768;   // K (blocked)
  bf16* vbf   = ws + off; off += (size_t)16384 * 768;   // V^T (blocked)
  bf16* xbf   = ws + off; off += (size_t)16384 * 768;   // GEMM out (row-major)
  bf16* a1buf = ws + off; off += (size_t)16384 * 3072;  // gelu acts
  float* pooled = (float*)(ws + off); off += 6144;

  dim3 blk(256);
  dim3 blk512(512);

  probe_kernel<<<1, 64, 0, stream>>>((const uint32_t*)ln_emb_g, dflag);

  for (int l = 0; l < 2; l++) {
    transpose_k<<<dim3(72, 24), blk, 0, stream>>>(Wqkv, (size_t)l * 768 * 2304, WqkvT + (size_t)l * 2304 * 768, 768, 2304, dflag);
    transpose_k<<<dim3(24, 24), blk, 0, stream>>>(Wo, (size_t)l * 768 * 768, WoT + (size_t)l * 768 * 768, 768, 768, dflag);
    transpose_k<<<dim3(96, 24), blk, 0, stream>>>(Wff1, (size_t)l * 768 * 3072, Wff1T + (size_t)l * 3072 * 768, 768, 3072, dflag);
    transpose_k<<<dim3(24, 96), blk, 0, stream>>>(Wff2, (size_t)l * 3072 * 768, Wff2T + (size_t)l * 768 * 3072, 3072, 768, dflag);
  }

  embed_ln_kernel<<<16384, blk, 0, stream>>>(input_ids, emb, pos_emb, ln_emb_g, ln_emb_b, hbuf, dflag);

  for (int l = 0; l < 2; l++) {
    gemm256<2><<<dim3(64, 9), blk512, 0, stream>>>(hbuf, WqkvT + (size_t)l * 2304 * 768, bqkv, (size_t)l * 2304,
                                                   nullptr, 2304, 768, qo, kbf, vbf, dflag);
    attn_kernel<<<3072, blk, 0, stream>>>(qo, kbf, vbf, attention_mask, rand_idx, qo);
    gemm_bt<0, true><<<dim3(128, 6), blk, 0, stream>>>(qo, WoT + (size_t)l * 768 * 768, bo, (size_t)l * 768,
                                                       xbf, 768, 768, nullptr, nullptr, nullptr, dflag);
    add_ln_kernel<<<4096, blk, 0, stream>>>(hbuf, xbf, ln1_g, ln1_b, (size_t)l * 768, dflag);
    gemm256<1><<<dim3(64, 12), blk512, 0, stream>>>(hbuf, Wff1T + (size_t)l * 3072 * 768, bff1, (size_t)l * 3072,
                                                    a1buf, 3072, 768, nullptr, nullptr, nullptr, dflag);
    gemm256<0><<<dim3(64, 3), blk512, 0, stream>>>(a1buf, Wff2T + (size_t)l * 768 * 3072, bff2, (size_t)l * 768,
                                                   xbf, 768, 3072, nullptr, nullptr, nullptr, dflag);
    add_ln_kernel<<<4096, blk, 0, stream>>>(hbuf, xbf, ln2_g, ln2_b, (size_t)l * 768, dflag);
  }

  pooler_kernel<<<4, dim3(768), 0, stream>>>(hbuf, Wp, bp, pooled, dflag);
  cls_kernel<<<1, blk, 0, stream>>>(pooled, Wc, bc, label, d_out, dflag);

  (void)in_sizes; (void)n_in; (void)out_size; (void)ws_size;
}

// Round 5
// 1496.701 us; speedup vs baseline: 1.0985x; 1.0985x over previous
//
#include <hip/hip_runtime.h>
#include <hip/hip_bf16.h>
#include <stdint.h>

// Model: B=4 S=4096 D=768 H=12 DH=64 BS=64 NB=64 NSEL=8 L=2 FF=3072 M=16384
// Round 10: fix rule-#20 violation in gemm256 epilogue.
//  Round 9's `for (P)` epilogue indexed acc[8][4] with runtime mh=P&1 ->
//  compiler demoted the whole accumulator to scratch (WRITE_SIZE 493 MB vs
//  100 MB ideal, VGPR 96 < 128 needed, MfmaUtil 14%). Fix: #pragma unroll
//  the P loops so every acc index is compile-time. No other changes.

using bf16 = __hip_bfloat16;
typedef __bf16 bf16x8 __attribute__((ext_vector_type(8)));
typedef __bf16 bf16x4 __attribute__((ext_vector_type(4)));
typedef float f32x4 __attribute__((ext_vector_type(4)));

__device__ __forceinline__ float b2f(bf16 x) { return __bfloat162float(x); }
__device__ __forceinline__ bf16 f2b(float x) { return __float2bfloat16(x); }
__device__ __forceinline__ __bf16 f2br(float x) {
  bf16 h = __float2bfloat16(x);
  return *reinterpret_cast<__bf16*>(&h);
}
__device__ __forceinline__ float br2f(__bf16 x) {
  bf16 t; *reinterpret_cast<__bf16*>(&t) = x; return __bfloat162float(t);
}
// flag=1: raw input buffers hold bf16; flag=0: f32.
__device__ __forceinline__ float ldf(const void* p, size_t i, int flag) {
  return flag ? __bfloat162float(((const bf16*)p)[i]) : ((const float*)p)[i];
}

__device__ __forceinline__ void gld_lds16(const bf16* g, bf16* l) {
  __builtin_amdgcn_global_load_lds((__attribute__((address_space(1))) void*)g,
                                   (__attribute__((address_space(3))) void*)l, 16, 0, 0);
}

__device__ __forceinline__ f32x4 mfma16(bf16x8 a, bf16x8 b, f32x4 c) {
  return __builtin_amdgcn_mfma_f32_16x16x32_bf16(a, b, c, 0, 0, 0);
}

// gelu(tanh approx) == x * sigmoid(2*0.79788456*(x + 0.044715 x^3))
__device__ __forceinline__ float gelu_f(float x) {
  const float z = 1.5957691216057308f * (x + 0.044715f * x * x * x);
  return x / (1.0f + __expf(-z));
}

// ---------------- dtype probe: ln_emb_g is all ones ----------------
__global__ void probe_kernel(const uint32_t* __restrict__ g, int* __restrict__ flag) {
  if (threadIdx.x == 0) flag[0] = (g[0] == 0x3F803F80u) ? 1 : 0;
}

// ---------------- weight transpose+convert ----------------
__global__ __launch_bounds__(256) void transpose_k(const void* __restrict__ in, size_t in_off,
                                                   bf16* __restrict__ out, int K, int N,
                                                   const int* __restrict__ dflag) {
  __shared__ float tile[32][33];
  const int flag = dflag[0];
  const int bx = blockIdx.x * 32;  // n
  const int by = blockIdx.y * 32;  // k
  const int tx = threadIdx.x & 31, ty = threadIdx.x >> 5;  // 32x8
#pragma unroll
  for (int i = 0; i < 32; i += 8)
    tile[ty + i][tx] = ldf(in, in_off + (size_t)(by + ty + i) * N + bx + tx, flag);
  __syncthreads();
#pragma unroll
  for (int i = 0; i < 32; i += 8)
    out[(size_t)(bx + ty + i) * K + by + tx] = f2b(tile[tx][ty + i]);
}

// ---------------- embedding + LN ----------------
__global__ __launch_bounds__(256) void embed_ln_kernel(
    const int* __restrict__ ids, const void* __restrict__ emb, const void* __restrict__ pos,
    const void* __restrict__ g, const void* __restrict__ bb, bf16* __restrict__ h,
    const int* __restrict__ dflag) {
  __shared__ float red[8];
  const int flag = dflag[0];
  const int tok = blockIdx.x;
  const int tid = threadIdx.x;
  const int s = tok & 4095;
  const size_t id = (size_t)ids[tok];
  float v[3]; float sum = 0.f, sq = 0.f;
#pragma unroll
  for (int i = 0; i < 3; i++) {
    const int d = tid + i * 256;
    v[i] = ldf(emb, id * 768 + d, flag) + ldf(pos, (size_t)s * 768 + d, flag);
    sum += v[i]; sq += v[i] * v[i];
  }
#pragma unroll
  for (int off = 32; off >= 1; off >>= 1) { sum += __shfl_down(sum, off); sq += __shfl_down(sq, off); }
  if ((tid & 63) == 0) { red[(tid >> 6) * 2] = sum; red[(tid >> 6) * 2 + 1] = sq; }
  __syncthreads();
  sum = red[0] + red[2] + red[4] + red[6];
  sq  = red[1] + red[3] + red[5] + red[7];
  const float mean = sum * (1.0f / 768.0f);
  const float var = sq * (1.0f / 768.0f) - mean * mean;
  const float rs = rsqrtf(var + 1e-12f);
  bf16* hr = h + (size_t)tok * 768;
#pragma unroll
  for (int i = 0; i < 3; i++) {
    const int d = tid + i * 256;
    hr[d] = f2b((v[i] - mean) * rs * ldf(g, d, flag) + ldf(bb, d, flag));
  }
}

// ---------------- residual add + LN (in-place on h), 1 wave per token ----------------
__global__ __launch_bounds__(256) void add_ln_kernel(
    bf16* __restrict__ h, const bf16* __restrict__ x,
    const void* __restrict__ g, const void* __restrict__ bb, size_t goff,
    const int* __restrict__ dflag) {
  const int flag = dflag[0];
  const int tid = threadIdx.x;
  const int wv = tid >> 6, lane = tid & 63;
  const int tok = blockIdx.x * 4 + wv;
  const size_t base = (size_t)tok * 768;

  float v[16];
  float sum = 0.f, sq = 0.f;
  const bf16x8 h0 = *(const bf16x8*)(h + base + lane * 8);
  const bf16x8 x0 = *(const bf16x8*)(x + base + lane * 8);
#pragma unroll
  for (int j = 0; j < 8; j++) {
    const float t = br2f(h0[j]) + br2f(x0[j]);
    v[j] = t; sum += t; sq += t * t;
  }
  if (lane < 32) {
    const bf16x8 h1 = *(const bf16x8*)(h + base + 512 + lane * 8);
    const bf16x8 x1 = *(const bf16x8*)(x + base + 512 + lane * 8);
#pragma unroll
    for (int j = 0; j < 8; j++) {
      const float t = br2f(h1[j]) + br2f(x1[j]);
      v[8 + j] = t; sum += t; sq += t * t;
    }
  }
#pragma unroll
  for (int off = 32; off >= 1; off >>= 1) { sum += __shfl_xor(sum, off); sq += __shfl_xor(sq, off); }
  const float mean = sum * (1.0f / 768.0f);
  const float var = sq * (1.0f / 768.0f) - mean * mean;
  const float rs = rsqrtf(var + 1e-12f);

  bf16x8 o0;
#pragma unroll
  for (int j = 0; j < 8; j++) {
    const int d = lane * 8 + j;
    o0[j] = f2br((v[j] - mean) * rs * ldf(g, goff + d, flag) + ldf(bb, goff + d, flag));
  }
  *(bf16x8*)(h + base + lane * 8) = o0;
  if (lane < 32) {
    bf16x8 o1;
#pragma unroll
    for (int j = 0; j < 8; j++) {
      const int d = 512 + lane * 8 + j;
      o1[j] = f2br((v[8 + j] - mean) * rs * ldf(g, goff + d, flag) + ldf(bb, goff + d, flag));
    }
    *(bf16x8*)(h + base + 512 + lane * 8) = o1;
  }
}

// ---------------- 256x256 GEMM: C[M,N] = A @ Bt^T + bias ----------------
// EPI 0: plain store. EPI 1: gelu. EPI 2: scatter into blocked q/k/vT.
// A row-major [M][K], Bt row-major [N][K]. 512 threads, 8 waves (2M x 4N),
// wave tile 128x64, BK=64. 2 LDS buffers (A 32KB + B 32KB each).
// LDS rows are 64 elems (128B); 16B chunk c of row r stored at slot c^(r&7)
// (inverse-swizzled global source, linear gld_lds dest; reads apply same XOR).
// NOTE: all acc[] indices must be compile-time (rule #20) -> epilogue P loops
// are fully unrolled.
template <int EPI>
__global__ __launch_bounds__(512) void gemm256(
    const bf16* __restrict__ A, const bf16* __restrict__ Bt,
    const void* __restrict__ bias, size_t bias_off, bf16* __restrict__ C,
    int N, int K,
    bf16* __restrict__ qout, bf16* __restrict__ kout, bf16* __restrict__ vout,
    const int* __restrict__ dflag) {
  __shared__ __align__(16) bf16 smem[65536];   // 2 x (A 16384 + B 16384)
  const int m0 = blockIdx.x * 256;
  const int n0 = blockIdx.y * 256;
  const int tid = threadIdx.x;
  const int lane = tid & 63;
  const int wv = tid >> 6;
  const int wm = wv >> 2, wn = wv & 3;         // 2 x 4 wave grid
  const int col = lane & 15, quad = lane >> 4;

  f32x4 acc[8][4] = {};

  // Staging geometry: per gld instr, thread t -> row t>>3 (of 64), slot t&7.
  // Global source chunk = slot ^ (row&7)  (row&7 invariant under +64 rows).
  const int rS = tid >> 3, slS = tid & 7;
  const int swz = (slS ^ (rS & 7)) << 3;       // element offset of source chunk
  const bf16* gA = A + (size_t)(m0 + rS) * K + swz;
  const bf16* gB = Bt + (size_t)(n0 + rS) * K + swz;
  const size_t rowstep = (size_t)64 * K;

  auto stage = [&](int buf, int kt) {
    bf16* dA = smem + buf * 32768;
    bf16* dB = dA + 16384;
    const int kk = kt * 64;
#pragma unroll
    for (int i = 0; i < 4; i++)
      gld_lds16(gA + (size_t)i * rowstep + kk, dA + i * 4096 + tid * 8);
#pragma unroll
    for (int i = 0; i < 4; i++)
      gld_lds16(gB + (size_t)i * rowstep + kk, dB + i * 4096 + tid * 8);
  };

  const int nkt = K >> 6;
  stage(0, 0);

  // Fragment read bases: row = base + {m,n}*16 + col; slot = (kh*4+quad)^(col&7)
  const int arow = wm * 128 + col;
  const int brow = wn * 64 + col;
  const int s7 = col & 7;

  for (int it = 0; it < nkt; ++it) {
    const int cur = it & 1;
    if (it + 1 < nkt) {
      stage(cur ^ 1, it + 1);
      asm volatile("s_waitcnt vmcnt(8)" ::: "memory");  // tile 'it' landed; next 8 in flight
    } else {
      asm volatile("s_waitcnt vmcnt(0)" ::: "memory");
    }
    __builtin_amdgcn_s_barrier();
    asm volatile("" ::: "memory");

    const bf16* cA = smem + cur * 32768;
    const bf16* cB = cA + 16384;
#pragma unroll
    for (int kh = 0; kh < 2; kh++) {
      const int ksl = ((kh * 4 + quad) ^ s7) << 3;
      bf16x8 bv[4];
#pragma unroll
      for (int n = 0; n < 4; n++)
        bv[n] = *(const bf16x8*)(cB + (brow + n * 16) * 64 + ksl);
#pragma unroll
      for (int mh = 0; mh < 2; mh++) {
        bf16x8 av[4];
#pragma unroll
        for (int m = 0; m < 4; m++)
          av[m] = *(const bf16x8*)(cA + (arow + (mh * 4 + m) * 16) * 64 + ksl);
        __builtin_amdgcn_s_setprio(1);
#pragma unroll
        for (int m = 0; m < 4; m++)
#pragma unroll
          for (int n = 0; n < 4; n++)
            acc[mh * 4 + m][n] = mfma16(av[m], bv[n], acc[mh * 4 + m][n]);
        __builtin_amdgcn_s_setprio(0);
        asm volatile("" ::: "memory");
        __builtin_amdgcn_s_barrier();    // phase lockstep; last one = iter-end barrier
      }
    }
  }

  const int flag = dflag[0];
  float bsv[4];
#pragma unroll
  for (int nt = 0; nt < 4; nt++)
    bsv[nt] = ldf(bias, bias_off + n0 + wn * 64 + nt * 16 + col, flag);

  if constexpr (EPI != 2) {
    // 4 passes of 64 rows, LDS pitch 264 elems, then vectorized copy-out.
    // P fully unrolled: acc indices compile-time (rule #20).
#pragma unroll
    for (int P = 0; P < 4; P++) {
      const int mh = P & 1;
      __syncthreads();
      if (wm == (P >> 1)) {
#pragma unroll
        for (int nt = 0; nt < 4; nt++)
#pragma unroll
          for (int m = 0; m < 4; m++)
#pragma unroll
            for (int r = 0; r < 4; r++) {
              float val = acc[mh * 4 + m][nt][r] + bsv[nt];
              if constexpr (EPI == 1) val = gelu_f(val);
              smem[(m * 16 + quad * 4 + r) * 264 + wn * 64 + nt * 16 + col] = f2b(val);
            }
      }
      __syncthreads();
#pragma unroll
      for (int j = 0; j < 4; j++) {
        const int c2 = j * 512 + tid;          // 2048 chunks of 8
        const int row = c2 >> 5, cc = c2 & 31;
        const bf16x8 vv = *(const bf16x8*)(smem + row * 264 + cc * 8);
        *(bf16x8*)(C + (size_t)(m0 + P * 64 + row) * N + n0 + cc * 8) = vv;
      }
    }
  } else {
    // QKV scatter: tile = 4 nb-blocks x 4 heads of one part (no straddle:
    // N=2304=3*768, 768%256==0; tokens 256 | 4096 per batch).
    const int part = n0 / 768;
    const int w0 = n0 - part * 768;
    const int h0 = w0 >> 6;
    const int bb = m0 >> 12;
    const int nb0 = (m0 >> 6) & 63;
#pragma unroll
    for (int P = 0; P < 4; P++) {
      const int mh = P & 1;
      __syncthreads();
      if (wm == (P >> 1)) {
        if (part < 2) {
#pragma unroll
          for (int nt = 0; nt < 4; nt++)
#pragma unroll
            for (int m = 0; m < 4; m++)
#pragma unroll
              for (int r = 0; r < 4; r++)
                smem[(m * 16 + quad * 4 + r) * 264 + wn * 64 + nt * 16 + col] =
                    f2b(acc[mh * 4 + m][nt][r] + bsv[nt]);
        } else {
          // V: stage transposed [ncol][pos], pitch 72
#pragma unroll
          for (int nt = 0; nt < 4; nt++) {
            const int ncol = wn * 64 + nt * 16 + col;
#pragma unroll
            for (int m = 0; m < 4; m++) {
              bf16x4 pk;
#pragma unroll
              for (int r = 0; r < 4; r++) pk[r] = f2br(acc[mh * 4 + m][nt][r] + bsv[nt]);
              *(bf16x4*)(smem + ncol * 72 + m * 16 + quad * 4) = pk;
            }
          }
        }
      }
      __syncthreads();
      const size_t nbase = (size_t)((bb * 12 + h0) * 64 + nb0 + P) * 4096;
      if (part < 2) {
        bf16* dst = (part == 0) ? qout : kout;
        const int pos = tid >> 3, pc = tid & 7;
#pragma unroll
        for (int j = 0; j < 4; j++) {
          const bf16x8 vv = *(const bf16x8*)(smem + pos * 264 + j * 64 + pc * 8);
          *(bf16x8*)(dst + nbase + (size_t)j * 262144 + pos * 64 + pc * 8) = vv;
        }
      } else {
        const int dh = tid >> 3, pc = tid & 7;
#pragma unroll
        for (int j = 0; j < 4; j++) {
          const bf16x8 vv = *(const bf16x8*)(smem + (j * 64 + dh) * 72 + pc * 8);
          *(bf16x8*)(vout + nbase + (size_t)j * 262144 + dh * 64 + pc * 8) = vv;
        }
      }
    }
  }
}

// ---------------- 128-tile GEMM (kept for AO): C[M,N] = A @ Bt^T + bias ----------------
// ABLK: A is blocked [bb][hh][nb][pos][dh]. Depth-2 pipeline, 3 buffers.
template <int EPI, bool ABLK>
__global__ __launch_bounds__(256) void gemm_bt(
    const bf16* __restrict__ A, const bf16* __restrict__ Bt,
    const void* __restrict__ bias, size_t bias_off, bf16* __restrict__ C,
    int N, int K,
    bf16* __restrict__ qout, bf16* __restrict__ kout, bf16* __restrict__ vout,
    const int* __restrict__ dflag) {
  __shared__ __align__(16) bf16 smem[24576];
  const int m0 = blockIdx.x * 128;
  const int n0 = blockIdx.y * 128;
  const int tid = threadIdx.x;
  const int lane = tid & 63;
  const int wv = tid >> 6;
  const int wm = wv >> 1, wn = wv & 1;
  const int col = lane & 15, quad = lane >> 4;

  f32x4 acc[4][4] = {};

  const int sr = tid >> 2;
  const int kc = ((tid & 3) - ((tid >> 4) & 3)) & 3;
  const int sc = kc * 8;
  const bf16* gA = A + (size_t)(m0 + sr) * K + sc;
  const bf16* gB = Bt + (size_t)(n0 + sr) * K + sc;
  const size_t rstep = (size_t)64 * K;

  size_t cb0 = 0, cb1 = 0;
  if constexpr (ABLK) {
    const int t0 = m0 + sr, t1 = t0 + 64;
    cb0 = (size_t)(t0 >> 12) * 3145728 + ((t0 >> 6) & 63) * 4096 + (t0 & 63) * 64;
    cb1 = (size_t)(t1 >> 12) * 3145728 + ((t1 >> 6) & 63) * 4096 + (t1 & 63) * 64;
  }

  const int sl = (quad + (col >> 2)) & 3;

  auto stage = [&](int buf, int kk) {
    bf16* dA = smem + buf * 8192;
    bf16* dB = dA + 4096;
    const bf16 *pA0, *pA1;
    if constexpr (ABLK) {
      const int c = kk + sc;
      const int hh = c >> 6, dh = c & 63;
      pA0 = A + cb0 + hh * 262144 + dh;
      pA1 = A + cb1 + hh * 262144 + dh;
    } else {
      pA0 = gA + kk; pA1 = gA + rstep + kk;
    }
    gld_lds16(pA0, dA + tid * 8);
    gld_lds16(pA1, dA + 2048 + tid * 8);
    gld_lds16(gB + kk, dB + tid * 8);
    gld_lds16(gB + rstep + kk, dB + 2048 + tid * 8);
  };

  const int nIter = K >> 5;
  stage(0, 0);
  stage(1, 32);

  int cur = 0, pf = 2;
  for (int it = 0; it < nIter; ++it) {
    if (it + 2 < nIter) {
      stage(pf, (it + 2) * 32);
      pf = (pf == 2) ? 0 : pf + 1;
      asm volatile("s_waitcnt vmcnt(8)" ::: "memory");
    } else if (it + 1 < nIter) {
      asm volatile("s_waitcnt vmcnt(4)" ::: "memory");
    } else {
      asm volatile("s_waitcnt vmcnt(0)" ::: "memory");
    }
    __builtin_amdgcn_s_barrier();
    asm volatile("" ::: "memory");

    const bf16* cA = smem + cur * 8192;
    const bf16* cB = cA + 4096;
    bf16x8 av[4], bv[4];
#pragma unroll
    for (int t = 0; t < 4; t++)
      av[t] = *(const bf16x8*)(cA + (wm * 64 + t * 16 + col) * 32 + sl * 8);
#pragma unroll
    for (int t = 0; t < 4; t++)
      bv[t] = *(const bf16x8*)(cB + (wn * 64 + t * 16 + col) * 32 + sl * 8);
#pragma unroll
    for (int mt = 0; mt < 4; mt++)
#pragma unroll
      for (int nt = 0; nt < 4; nt++)
        acc[mt][nt] = mfma16(av[mt], bv[nt], acc[mt][nt]);

    asm volatile("" ::: "memory");
    __builtin_amdgcn_s_barrier();
    cur = (cur == 2) ? 0 : cur + 1;
  }

  const int flag = dflag[0];
  float bsv[4];
#pragma unroll
  for (int nt = 0; nt < 4; nt++)
    bsv[nt] = ldf(bias, bias_off + n0 + wn * 64 + nt * 16 + col, flag);

  // Single-pass LDS-staged coalesced store (EPI 0/1 only used for AO here).
#pragma unroll
  for (int nt = 0; nt < 4; nt++)
#pragma unroll
    for (int mt = 0; mt < 4; mt++)
#pragma unroll
      for (int r = 0; r < 4; r++) {
        float val = acc[mt][nt][r] + bsv[nt];
        if constexpr (EPI == 1) val = gelu_f(val);
        smem[(wm * 64 + mt * 16 + quad * 4 + r) * 136 + wn * 64 + nt * 16 + col] = f2b(val);
      }
  __syncthreads();
#pragma unroll
  for (int rr = 0; rr < 8; rr++) {
    const int row = rr * 16 + (tid >> 4);
    const int ch = tid & 15;
    const bf16x8 vv = *(const bf16x8*)(smem + row * 136 + ch * 8);
    *(bf16x8*)(C + (size_t)(m0 + row) * N + n0 + ch * 8) = vv;
  }
  (void)qout; (void)kout; (void)vout;
}

// ---------------- block-sparse flash attention, full batch ----------------
__global__ __launch_bounds__(256, 4) void attn_kernel(
    const bf16* q, const bf16* __restrict__ kmat, const bf16* __restrict__ vT,
    const int* __restrict__ amask, const int* __restrict__ rand_idx, bf16* o) {
  __shared__ __align__(16) bf16 sK[2][4096];
  __shared__ __align__(16) bf16 sV[2][4096];
  const int idx = blockIdx.x;
  const int nb = idx & 63;
  const int bh = idx >> 6;
  const int bb = bh / 12;
  const int tid = threadIdx.x;
  const int wv = tid >> 6, lane = tid & 63;
  const int col = lane & 15, quad = lane >> 4;

  int sel[8];
  sel[0] = 0; sel[1] = (nb + 63) & 63; sel[2] = nb; sel[3] = (nb + 1) & 63;
  sel[4] = 63;
  sel[5] = rand_idx[nb * 3 + 0];
  sel[6] = rand_idx[nb * 3 + 1];
  sel[7] = rand_idx[nb * 3 + 2];

  const size_t bhbase = (size_t)bh * 64;

  const bf16* qb = q + (bhbase + nb) * 4096;
  const int qrow = wv * 16 + col;
  const bf16x8 bq0 = *(const bf16x8*)(qb + qrow * 64 + quad * 8);
  const bf16x8 bq1 = *(const bf16x8*)(qb + qrow * 64 + 32 + quad * 8);

  unsigned long long bal[8];
#pragma unroll
  for (int sb = 0; sb < 8; sb++)
    bal[sb] = __ballot(amask[bb * 4096 + sel[sb] * 64 + lane] > 0);

  const int srow = tid >> 3, sslot = tid & 7;
  const int sw0 = ((sslot ^ (srow & 7)) << 3);

  auto stage = [&](int buf, int blk) {
    const bf16* gk = kmat + (bhbase + blk) * 4096;
    const bf16* gv = vT + (bhbase + blk) * 4096;
    bf16* dk = sK[buf];
    bf16* dv = sV[buf];
    gld_lds16(gk + srow * 64 + sw0, dk + tid * 8);
    gld_lds16(gk + (srow + 32) * 64 + sw0, dk + 2048 + tid * 8);
    gld_lds16(gv + srow * 64 + sw0, dv + tid * 8);
    gld_lds16(gv + (srow + 32) * 64 + sw0, dv + 2048 + tid * 8);
  };

  f32x4 oacc[4] = {};
  float mrun = -1e30f, lrun = 0.0f;

  stage(0, sel[0]);

#pragma unroll
  for (int sb = 0; sb < 8; sb++) {
    const int cur = sb & 1;
    if (sb < 7) {
      stage(cur ^ 1, sel[sb + 1]);
      asm volatile("s_waitcnt vmcnt(4)" ::: "memory");
    } else {
      asm volatile("s_waitcnt vmcnt(0)" ::: "memory");
    }
    __builtin_amdgcn_s_barrier();
    asm volatile("" ::: "memory");

    const bf16* kb = sK[cur];
    f32x4 t[4];
#pragma unroll
    for (int c = 0; c < 4; c++) {
      const int r = c * 16 + col;
      const bf16x8 ak0 = *(const bf16x8*)(kb + r * 64 + ((quad ^ (r & 7)) << 3));
      const bf16x8 ak1 = *(const bf16x8*)(kb + r * 64 + (((4 + quad) ^ (r & 7)) << 3));
      f32x4 s4 = {};
      s4 = mfma16(ak0, bq0, s4);
      s4 = mfma16(ak1, bq1, s4);
      t[c] = s4;
    }
#pragma unroll
    for (int c = 0; c < 4; c++)
#pragma unroll
      for (int r = 0; r < 4; r++) t[c][r] *= 0.125f;
    if (bal[sb] != ~0ull) {
#pragma unroll
      for (int c = 0; c < 4; c++)
#pragma unroll
        for (int r = 0; r < 4; r++)
          if (!((bal[sb] >> (c * 16 + quad * 4 + r)) & 1)) t[c][r] -= 1e9f;
    }

    float pm = t[0][0];
#pragma unroll
    for (int c = 0; c < 4; c++)
#pragma unroll
      for (int r = 0; r < 4; r++) pm = fmaxf(pm, t[c][r]);
    pm = fmaxf(pm, __shfl_xor(pm, 16));
    pm = fmaxf(pm, __shfl_xor(pm, 32));

    const float mnew = fmaxf(mrun, pm);
    const float scale = __expf(mrun - mnew);
    float ps = 0.0f;
    bf16x8 pa8[2];
#pragma unroll
    for (int c = 0; c < 4; c++)
#pragma unroll
      for (int r = 0; r < 4; r++) {
        const float p = __expf(t[c][r] - mnew);
        ps += p;
        pa8[c >> 1][(c & 1) * 4 + r] = f2br(p);
      }
    ps += __shfl_xor(ps, 16);
    ps += __shfl_xor(ps, 32);
    lrun = lrun * scale + ps;
    mrun = mnew;

    float sc[4];
#pragma unroll
    for (int r = 0; r < 4; r++) sc[r] = __shfl(scale, quad * 4 + r);
#pragma unroll
    for (int nt = 0; nt < 4; nt++)
#pragma unroll
      for (int r = 0; r < 4; r++) oacc[nt][r] *= sc[r];

    const bf16* vb = sV[cur];
#pragma unroll
    for (int pr = 0; pr < 2; pr++) {
      const int g0 = 4 * pr + (quad >> 1);
      const int g1 = g0 + 2;
      const int so = (quad & 1) * 4;
#pragma unroll
      for (int nt = 0; nt < 4; nt++) {
        const int dh = nt * 16 + col;
        const bf16x4 bv0 = *(const bf16x4*)(vb + dh * 64 + ((g0 ^ (col & 7)) << 3) + so);
        const bf16x4 bv1 = *(const bf16x4*)(vb + dh * 64 + ((g1 ^ (col & 7)) << 3) + so);
        const bf16x8 bv8 = __builtin_shufflevector(bv0, bv1, 0, 1, 2, 3, 4, 5, 6, 7);
        oacc[nt] = mfma16(pa8[pr], bv8, oacc[nt]);
      }
    }
    asm volatile("" ::: "memory");
    __builtin_amdgcn_s_barrier();
  }

  const float invl = 1.0f / lrun;
  float iv[4];
#pragma unroll
  for (int r = 0; r < 4; r++) iv[r] = __shfl(invl, quad * 4 + r);
  bf16* ob = o + (bhbase + nb) * 4096;
#pragma unroll
  for (int nt = 0; nt < 4; nt++)
#pragma unroll
    for (int r = 0; r < 4; r++)
      ob[(wv * 16 + quad * 4 + r) * 64 + nt * 16 + col] = f2b(oacc[nt][r] * iv[r]);
}

// ---------------- pooler ----------------
__global__ __launch_bounds__(768) void pooler_kernel(
    const bf16* __restrict__ h, const void* __restrict__ Wp,
    const void* __restrict__ bp, float* __restrict__ pooled,
    const int* __restrict__ dflag) {
  __shared__ float hrow[768];
  const int flag = dflag[0];
  const int bb = blockIdx.x;
  const int j = threadIdx.x;
  hrow[j] = b2f(h[(size_t)bb * 4096 * 768 + j]);
  __syncthreads();
  float acc = 0.0f;
#pragma unroll 8
  for (int d = 0; d < 768; d++) acc += hrow[d] * ldf(Wp, (size_t)d * 768 + j, flag);
  pooled[bb * 768 + j] = tanhf(acc + ldf(bp, j, flag));
}

// ---------------- classifier + double-softmax loss ----------------
__global__ __launch_bounds__(256) void cls_kernel(
    const float* __restrict__ pooled, const void* __restrict__ Wc, const void* __restrict__ bc,
    const int* __restrict__ label, void* __restrict__ out, const int* __restrict__ dflag) {
  __shared__ float lsum[8];
  const int flag = dflag[0];
  const int tid = threadIdx.x;
  const int p = tid >> 5, i = tid & 31;
  const int bb = p >> 1, c = p & 1;
  float acc = 0.0f;
  for (int d = i; d < 768; d += 32) acc += pooled[bb * 768 + d] * ldf(Wc, (size_t)d * 2 + c, flag);
#pragma unroll
  for (int off = 16; off >= 1; off >>= 1) acc += __shfl_xor(acc, off);
  if (i == 0) lsum[p] = acc;
  __syncthreads();
  if (tid == 0) {
    float res[9];
    float loss = 0.0f;
    for (int b = 0; b < 4; b++) {
      const float l0 = lsum[b * 2 + 0] + ldf(bc, 0, flag);
      const float l1 = lsum[b * 2 + 1] + ldf(bc, 1, flag);
      const float m = fmaxf(l0, l1);
      const float e0 = expf(l0 - m), e1 = expf(l1 - m);
      const float s = e0 + e1;
      const float p0 = e0 / s, p1 = e1 / s;
      res[b * 2] = p0; res[b * 2 + 1] = p1;
      const float mm = fmaxf(p0, p1);
      const float lse = mm + logf(expf(p0 - mm) + expf(p1 - mm));
      const float chosen = (label[b] == 0) ? p0 : p1;
      loss -= (chosen - lse);
    }
    res[8] = loss * 0.25f;
    if (flag) { bf16* o = (bf16*)out; for (int j = 0; j < 9; j++) o[j] = f2b(res[j]); }
    else      { float* o = (float*)out; for (int j = 0; j < 9; j++) o[j] = res[j]; }
  }
}

extern "C" void kernel_launch(void* const* d_in, const int* in_sizes, int n_in,
                              void* d_out, int out_size, void* d_ws, size_t ws_size,
                              hipStream_t stream) {
  const int* input_ids      = (const int*)d_in[0];
  const int* attention_mask = (const int*)d_in[1];
  const int* label          = (const int*)d_in[2];
  const int* rand_idx       = (const int*)d_in[3];
  const void* emb      = d_in[4];
  const void* pos_emb  = d_in[5];
  const void* ln_emb_g = d_in[6];
  const void* ln_emb_b = d_in[7];
  const void* Wqkv = d_in[8];
  const void* bqkv = d_in[9];
  const void* Wo   = d_in[10];
  const void* bo   = d_in[11];
  const void* ln1_g = d_in[12];
  const void* ln1_b = d_in[13];
  const void* Wff1 = d_in[14];
  const void* bff1 = d_in[15];
  const void* Wff2 = d_in[16];
  const void* bff2 = d_in[17];
  const void* ln2_g = d_in[18];
  const void* ln2_b = d_in[19];
  const void* Wp = d_in[20];
  const void* bp = d_in[21];
  const void* Wc = d_in[22];
  const void* bc = d_in[23];

  bf16* ws = (bf16*)d_ws;
  size_t off = 0;
  int* dflag = (int*)(ws + off); off += 8;
  bf16* WqkvT = ws + off; off += (size_t)2 * 2304 * 768;
  bf16* WoT   = ws + off; off += (size_t)2 * 768 * 768;
  bf16* Wff1T = ws + off; off += (size_t)2 * 3072 * 768;
  bf16* Wff2T = ws + off; off += (size_t)2 * 768 * 3072;
  bf16* hbuf  = ws + off; off += (size_t)16384 * 768;
  bf16* qo    = ws + off; off += (size_t)16384 * 768;   // Q then O (blocked)
  bf16* kbf   = ws + off; off += (size_t)16384 * 768;   // K (blocked)
  bf16* vbf   = ws + off; off += (size_t)16384 * 768;   // V^T (blocked)
  bf16* xbf   = ws + off; off += (size_t)16384 * 768;   // GEMM out (row-major)
  bf16* a1buf = ws + off; off += (size_t)16384 * 3072;  // gelu acts
  float* pooled = (float*)(ws + off); off += 6144;

  dim3 blk(256);
  dim3 blk512(512);

  probe_kernel<<<1, 64, 0, stream>>>((const uint32_t*)ln_emb_g, dflag);

  for (int l = 0; l < 2; l++) {
    transpose_k<<<dim3(72, 24), blk, 0, stream>>>(Wqkv, (size_t)l * 768 * 2304, WqkvT + (size_t)l * 2304 * 768, 768, 2304, dflag);
    transpose_k<<<dim3(24, 24), blk, 0, stream>>>(Wo, (size_t)l * 768 * 768, WoT + (size_t)l * 768 * 768, 768, 768, dflag);
    transpose_k<<<dim3(96, 24), blk, 0, stream>>>(Wff1, (size_t)l * 768 * 3072, Wff1T + (size_t)l * 3072 * 768, 768, 3072, dflag);
    transpose_k<<<dim3(24, 96), blk, 0, stream>>>(Wff2, (size_t)l * 3072 * 768, Wff2T + (size_t)l * 768 * 3072, 3072, 768, dflag);
  }

  embed_ln_kernel<<<16384, blk, 0, stream>>>(input_ids, emb, pos_emb, ln_emb_g, ln_emb_b, hbuf, dflag);

  for (int l = 0; l < 2; l++) {
    gemm256<2><<<dim3(64, 9), blk512, 0, stream>>>(hbuf, WqkvT + (size_t)l * 2304 * 768, bqkv, (size_t)l * 2304,
                                                   nullptr, 2304, 768, qo, kbf, vbf, dflag);
    attn_kernel<<<3072, blk, 0, stream>>>(qo, kbf, vbf, attention_mask, rand_idx, qo);
    gemm_bt<0, true><<<dim3(128, 6), blk, 0, stream>>>(qo, WoT + (size_t)l * 768 * 768, bo, (size_t)l * 768,
                                                       xbf, 768, 768, nullptr, nullptr, nullptr, dflag);
    add_ln_kernel<<<4096, blk, 0, stream>>>(hbuf, xbf, ln1_g, ln1_b, (size_t)l * 768, dflag);
    gemm256<1><<<dim3(64, 12), blk512, 0, stream>>>(hbuf, Wff1T + (size_t)l * 3072 * 768, bff1, (size_t)l * 3072,
                                                    a1buf, 3072, 768, nullptr, nullptr, nullptr, dflag);
    gemm256<0><<<dim3(64, 3), blk512, 0, stream>>>(a1buf, Wff2T + (size_t)l * 768 * 3072, bff2, (size_t)l * 768,
                                                   xbf, 768, 3072, nullptr, nullptr, nullptr, dflag);
    add_ln_kernel<<<4096, blk, 0, stream>>>(hbuf, xbf, ln2_g, ln2_b, (size_t)l * 768, dflag);
  }

  pooler_kernel<<<4, dim3(768), 0, stream>>>(hbuf, Wp, bp, pooled, dflag);
  cls_kernel<<<1, blk, 0, stream>>>(pooled, Wc, bc, label, d_out, dflag);

  (void)in_sizes; (void)n_in; (void)out_size; (void)ws_size;
}